// Round 6
// baseline (3079.441 us; speedup 1.0000x reference)
//
#include <hip/hip_runtime.h>
#include <hip/hip_bf16.h>
#include <stdint.h>

#define M_DIM 8192
#define N_DIM 4096
#define K_DIM 4096

typedef __attribute__((ext_vector_type(8))) __bf16 bf16x8;
typedef __attribute__((ext_vector_type(4))) float f32x4;

__device__ inline unsigned short f2bf(float f) {
  unsigned u = __builtin_bit_cast(unsigned, f);
  u += 0x7FFF + ((u >> 16) & 1);   // round-to-nearest-even
  return (unsigned short)(u >> 16);
}

__device__ inline void async_copy16(const void* g, void* l) {
  __builtin_amdgcn_global_load_lds(
      (const __attribute__((address_space(1))) unsigned int*)g,
      (__attribute__((address_space(3))) unsigned int*)l, 16, 0, 0);
}

// ---------- fused prep: blocks [0,4096) build W_eff; [4096,6144) cvt x ----------
__global__ __launch_bounds__(256) void prep_kernel(
    const float* __restrict__ x, unsigned short* __restrict__ xb,
    const int* __restrict__ Wq, const float* __restrict__ scale,
    const float* __restrict__ zero, const float* __restrict__ A,
    const float* __restrict__ Bm, unsigned short* __restrict__ Weff) {
  int t = threadIdx.x;
  if (blockIdx.x < 4096) {
    __shared__ float sA[64 * 17];
    __shared__ float sB[16 * 64];
    int bo = blockIdx.x >> 6;
    int bi = blockIdx.x & 63;
    int o0 = bo * 64, i0 = bi * 64;
    for (int j = t; j < 1024; j += 256) sA[(j >> 4) * 17 + (j & 15)] = A[i0 * 16 + j];
    for (int j = t; j < 1024; j += 256) sB[j] = Bm[(j >> 6) * N_DIM + o0 + (j & 63)];
    __syncthreads();
    for (int e = 0; e < 16; ++e) {
      int idx = e * 256 + t;
      int oo = idx >> 6, ii = idx & 63;
      int o = o0 + oo;
      float sc = scale[o * 64 + bi];
      float zp = zero[o * 64 + bi];
      float w = ((float)Wq[(size_t)o * K_DIM + i0 + ii] - zp) * sc;
      float acc = 0.f;
#pragma unroll
      for (int r = 0; r < 16; ++r) acc += sA[ii * 17 + r] * sB[r * 64 + oo];
      w += 2.0f * acc;
      Weff[(size_t)o * K_DIM + i0 + ii] = f2bf(w);
    }
  } else {
    int i = (blockIdx.x - 4096) * 256 + t;
    int stride = 2048 * 256;
    int n4 = (M_DIM * K_DIM) / 4;
    for (; i < n4; i += stride) {
      float4 v = reinterpret_cast<const float4*>(x)[i];
      ushort4 o;
      o.x = f2bf(v.x); o.y = f2bf(v.y); o.z = f2bf(v.z); o.w = f2bf(v.w);
      reinterpret_cast<ushort4*>(xb)[i] = o;
    }
  }
}

// ---------- 256x256 8-phase bf16 GEMM, BK=32, 64KB LDS -> 2 blocks/CU ----------
#define BAR() __builtin_amdgcn_s_barrier()
#define SB()  __builtin_amdgcn_sched_barrier(0)
#define WAIT_VM1() do { asm volatile("s_waitcnt vmcnt(1)" ::: "memory"); } while (0)
#define WAIT_VM2() do { asm volatile("s_waitcnt vmcnt(2)" ::: "memory"); } while (0)

// region = [128][32] bf16 (4096 ushort). 16B chunk c of row lives at physical
// column (c ^ (row&3)) -- involution, pre-applied on the global staging source.
__device__ __forceinline__ bf16x8 lds_frag(const unsigned short* region, int row, int c) {
  return *reinterpret_cast<const bf16x8*>(region + row * 32 + ((c ^ (row & 3)) << 3));
}

__device__ __forceinline__ void readA(const unsigned short* reg, int mh, int lc, int lr,
                                      bf16x8 a[4]) {
#pragma unroll
  for (int m = 0; m < 4; ++m) a[m] = lds_frag(reg, mh * 64 + m * 16 + lc, lr);
}

__device__ __forceinline__ void readB(const unsigned short* reg, int nh, int rB, int lc, int lr,
                                      bf16x8 b[2]) {
#pragma unroll
  for (int n = 0; n < 2; ++n) b[n] = lds_frag(reg, rB + (nh * 2 + n) * 16 + lc, lr);
}

__device__ __forceinline__ void mfma_oct(const bf16x8 a[4], const bf16x8 b[2],
                                         f32x4 acc[8][4], int mh, int nh) {
  __builtin_amdgcn_s_setprio(1);
#pragma unroll
  for (int m = 0; m < 4; ++m)
#pragma unroll
    for (int n = 0; n < 2; ++n)
      acc[mh * 4 + m][nh * 2 + n] = __builtin_amdgcn_mfma_f32_16x16x32_bf16(
          a[m], b[n], acc[mh * 4 + m][nh * 2 + n], 0, 0, 0);
  __builtin_amdgcn_s_setprio(0);
}

__global__ __launch_bounds__(512, 4) void gemm_kernel(
    const unsigned short* __restrict__ xb, const unsigned short* __restrict__ wb,
    const float* __restrict__ bias, float* __restrict__ out) {
  // LDS: 2 bufs x [A0|A1|B0|B1], each region 128x32 bf16 (4096 ushort) = 64 KiB
  __shared__ unsigned short lds[32768];

  int bid = blockIdx.x;
  int swz = (bid & 7) * 64 + (bid >> 3);   // bijective: 512 % 8 == 0
  int mt = swz >> 4, nt = swz & 15;
  int m0 = mt * 256, n0 = nt * 256;

  int tid = threadIdx.x;
  int w = tid >> 6, lane = tid & 63;
  int wr = w >> 2, wc = w & 3;             // 2 x 4 waves; per-wave out = 128 x 64
  int lr = lane >> 4, lc = lane & 15;
  int rB = (wc & 1) * 64;

  // staging: thread tid stages chunk tid of a region: row = tid>>2, phys c = tid&3,
  // global chunk cg = c ^ (row&3). Linear LDS dest (wave-uniform base + lane*16).
  int rS = tid >> 2, cgS = (tid & 3) ^ (rS & 3);

  const unsigned short* sA00 = xb + (size_t)(m0 + rS) * K_DIM + cgS * 8;
  const unsigned short* sB00 = wb + (size_t)(n0 + rS) * K_DIM + cgS * 8;

#define STAGE_A(h, buf, kt) \
    async_copy16(sA00 + (size_t)(h) * 128 * K_DIM + (size_t)(kt), \
                 &lds[(buf) * 16384 + (h) * 4096 + tid * 8])
#define STAGE_B(h, buf, kt) \
    async_copy16(sB00 + (size_t)(h) * 128 * K_DIM + (size_t)(kt), \
                 &lds[(buf) * 16384 + 8192 + (h) * 4096 + tid * 8])

  const unsigned short* aR[2] = { &lds[wr * 4096], &lds[16384 + wr * 4096] };
  const unsigned short* bR[2] = { &lds[8192 + (wc >> 1) * 4096],
                                  &lds[16384 + 8192 + (wc >> 1) * 4096] };

  f32x4 acc[8][4];
#pragma unroll
  for (int i = 0; i < 8; ++i)
#pragma unroll
    for (int j = 0; j < 4; ++j) acc[i][j] = f32x4{0.f, 0.f, 0.f, 0.f};

  // prologue: buf0 <- tile0 (4 regions, oldest), buf1 <- tile1 (4 regions)
  STAGE_B(0, 0, 0); STAGE_B(1, 0, 0); STAGE_A(0, 0, 0); STAGE_A(1, 0, 0);
  STAGE_B(0, 1, 32); STAGE_B(1, 1, 32); STAGE_A(0, 1, 32); STAGE_A(1, 1, 32);
  asm volatile("s_waitcnt vmcnt(4)" ::: "memory");   // tile0 landed
  BAR(); SB();

  bf16x8 aU[4], aV[4], b0[2], b1[2];
  readA(aR[0], 0, lc, lr, aU); readB(bR[0], 0, rB, lc, lr, b0);  // pre-read P1
  SB();

#pragma unroll 1
  for (int i = 0; i < 64; ++i) {
    int k2 = ((2 * i + 2) & 127) * 32;     // tile t+2 (wrap harmless at tail)
    int k3 = ((2 * i + 3) & 127) * 32;     // tile t+3

    // P1: Q(0,0)=aU,b0        read(P2): b1 <- buf0.B nh1
    readB(bR[0], 1, rB, lc, lr, b1);
    SB();
    mfma_oct(aU, b0, acc, 0, 0);
    SB(); BAR(); SB();
    // P2: Q(0,1)=aU,b1        read(P3): aV <- buf0.A mh1
    readA(aR[0], 1, lc, lr, aV);
    SB();
    mfma_oct(aU, b1, acc, 0, 1);
    SB(); BAR(); SB();
    // P3: Q(1,0)=aV,b0        stage buf0.B0(t+2)  [B(t) last read-issue P1]
    SB(); STAGE_B(0, 0, k2); SB();
    mfma_oct(aV, b0, acc, 1, 0);
    SB(); BAR(); SB();
    // P4: Q(1,1)=aV,b1        seam: buf1(t+1) landed; read(P5): aU,b0 <- buf1
    //                         stage buf0.B1(t+2)
    WAIT_VM1(); SB();
    readA(aR[1], 0, lc, lr, aU); readB(bR[1], 0, rB, lc, lr, b0);
    SB(); STAGE_B(1, 0, k2); SB();
    mfma_oct(aV, b1, acc, 1, 1);
    SB(); BAR(); SB();
    // P5: Q(0,0)=aU,b0        read(P6): b1 <- buf1.B nh1   stage buf0.A0(t+2)
    readB(bR[1], 1, rB, lc, lr, b1);
    SB(); STAGE_A(0, 0, k2); SB();
    mfma_oct(aU, b0, acc, 0, 0);
    SB(); BAR(); SB();
    // P6: Q(0,1)=aU,b1        read(P7): aV <- buf1.A mh1   stage buf0.A1(t+2)
    readA(aR[1], 1, lc, lr, aV);
    SB(); STAGE_A(1, 0, k2); SB();
    mfma_oct(aU, b1, acc, 0, 1);
    SB(); BAR(); SB();
    // P7: Q(1,0)=aV,b0        stage buf1.B0,B1(t+3)  [B(t+1) last read-issue P5]
    SB(); STAGE_B(0, 1, k3); STAGE_B(1, 1, k3); SB();
    mfma_oct(aV, b0, acc, 1, 0);
    SB(); BAR(); SB();
    // P8: Q(1,1)=aV,b1        seam: buf0(t+2) landed; read(P1'): aU,b0 <- buf0
    //                         stage buf1.A0,A1(t+3)  [A(t+1) last read-issue P6]
    WAIT_VM2(); SB();
    readA(aR[0], 0, lc, lr, aU); readB(bR[0], 0, rB, lc, lr, b0);
    SB(); STAGE_A(0, 1, k3); STAGE_A(1, 1, k3); SB();
    mfma_oct(aV, b1, acc, 1, 1);
    SB(); BAR(); SB();
  }
  asm volatile("s_waitcnt vmcnt(0) lgkmcnt(0)" ::: "memory");  // drain strays

  // epilogue: 16x16 C/D layout col=lane&15, row=(lane>>4)*4+j  [m89/m91]
#pragma unroll
  for (int ni = 0; ni < 4; ++ni) {
    int n = n0 + wc * 64 + ni * 16 + lc;
    float bv = bias[n];
#pragma unroll
    for (int mi = 0; mi < 8; ++mi) {
      int mb = m0 + wr * 128 + mi * 16 + lr * 4;
#pragma unroll
      for (int j = 0; j < 4; ++j)
        out[(size_t)(mb + j) * N_DIM + n] = acc[mi][ni][j] + bv;
    }
  }
#undef STAGE_A
#undef STAGE_B
}

extern "C" void kernel_launch(void* const* d_in, const int* in_sizes, int n_in,
                              void* d_out, int out_size, void* d_ws, size_t ws_size,
                              hipStream_t stream) {
  const float* x     = (const float*)d_in[0];
  const int*   Wq    = (const int*)d_in[1];
  const float* scale = (const float*)d_in[2];
  const float* zero  = (const float*)d_in[3];
  const float* lA    = (const float*)d_in[4];
  const float* lB    = (const float*)d_in[5];
  const float* bias  = (const float*)d_in[6];
  float* out = (float*)d_out;

  unsigned short* xb = (unsigned short*)d_ws;                                      // 64 MB
  unsigned short* wb = (unsigned short*)((char*)d_ws + (size_t)M_DIM * K_DIM * 2); // +32 MB

  prep_kernel<<<6144, 256, 0, stream>>>(x, xb, Wq, scale, zero, lA, lB, wb);
  gemm_kernel<<<512, 512, 0, stream>>>(xb, wb, bias, out);
}

// Round 7
// 325.059 us; speedup vs baseline: 9.4735x; 9.4735x over previous
//
#include <hip/hip_runtime.h>
#include <hip/hip_bf16.h>
#include <stdint.h>

#define M_DIM 8192
#define N_DIM 4096
#define K_DIM 4096

typedef __attribute__((ext_vector_type(8))) __bf16 bf16x8;
typedef __attribute__((ext_vector_type(4))) float f32x4;

__device__ inline unsigned short f2bf(float f) {
  unsigned u = __builtin_bit_cast(unsigned, f);
  u += 0x7FFF + ((u >> 16) & 1);   // round-to-nearest-even
  return (unsigned short)(u >> 16);
}

__device__ inline void async_copy16(const void* g, void* l) {
  __builtin_amdgcn_global_load_lds(
      (const __attribute__((address_space(1))) unsigned int*)g,
      (__attribute__((address_space(3))) unsigned int*)l, 16, 0, 0);
}

// ---------- fused prep: blocks [0,4096) build W_eff; [4096,6144) cvt x ----------
__global__ __launch_bounds__(256) void prep_kernel(
    const float* __restrict__ x, unsigned short* __restrict__ xb,
    const int* __restrict__ Wq, const float* __restrict__ scale,
    const float* __restrict__ zero, const float* __restrict__ A,
    const float* __restrict__ Bm, unsigned short* __restrict__ Weff) {
  int t = threadIdx.x;
  if (blockIdx.x < 4096) {
    __shared__ float sA[64 * 17];
    __shared__ float sB[16 * 64];
    int bo = blockIdx.x >> 6;
    int bi = blockIdx.x & 63;
    int o0 = bo * 64, i0 = bi * 64;
    for (int j = t; j < 1024; j += 256) sA[(j >> 4) * 17 + (j & 15)] = A[i0 * 16 + j];
    for (int j = t; j < 1024; j += 256) sB[j] = Bm[(j >> 6) * N_DIM + o0 + (j & 63)];
    __syncthreads();
    for (int e = 0; e < 16; ++e) {
      int idx = e * 256 + t;
      int oo = idx >> 6, ii = idx & 63;
      int o = o0 + oo;
      float sc = scale[o * 64 + bi];
      float zp = zero[o * 64 + bi];
      float w = ((float)Wq[(size_t)o * K_DIM + i0 + ii] - zp) * sc;
      float acc = 0.f;
#pragma unroll
      for (int r = 0; r < 16; ++r) acc += sA[ii * 17 + r] * sB[r * 64 + oo];
      w += 2.0f * acc;
      Weff[(size_t)o * K_DIM + i0 + ii] = f2bf(w);
    }
  } else {
    int i = (blockIdx.x - 4096) * 256 + t;
    int stride = 2048 * 256;
    int n4 = (M_DIM * K_DIM) / 4;
    for (; i < n4; i += stride) {
      float4 v = reinterpret_cast<const float4*>(x)[i];
      ushort4 o;
      o.x = f2bf(v.x); o.y = f2bf(v.y); o.z = f2bf(v.z); o.w = f2bf(v.w);
      reinterpret_cast<ushort4*>(xb)[i] = o;
    }
  }
}

// ---------- 256x256 8-phase bf16 GEMM, m201-exact phase discipline ----------
#define BAR() __builtin_amdgcn_s_barrier()
#define SB()  __builtin_amdgcn_sched_barrier(0)
#define WAIT_LGKM0() do { asm volatile("s_waitcnt lgkmcnt(0)" ::: "memory"); SB(); } while (0)
#define HINT_LGKM8() do { asm volatile("s_waitcnt lgkmcnt(8)" ::: "memory"); } while (0)
#define WAIT_VM8()   do { asm volatile("s_waitcnt vmcnt(8)" ::: "memory"); } while (0)

// swizzled LDS fragment read: region is [128][64] bf16 half-tile; 16B chunk c of
// row lives at physical column (c ^ (row&7)). Measured 0 bank conflicts (R2/R4/R5).
__device__ __forceinline__ bf16x8 lds_frag(const unsigned short* region, int row, int c) {
  return *reinterpret_cast<const bf16x8*>(region + row * 64 + ((c ^ (row & 7)) << 3));
}

__device__ __forceinline__ void readA(const unsigned short* reg, int mh, int lc, int lr,
                                      bf16x8 a[4][2]) {
#pragma unroll
  for (int m = 0; m < 4; ++m) {
    int row = mh * 64 + m * 16 + lc;
#pragma unroll
    for (int kk = 0; kk < 2; ++kk) a[m][kk] = lds_frag(reg, row, kk * 4 + lr);
  }
}

__device__ __forceinline__ void readB(const unsigned short* reg, int nh, int rB, int lc, int lr,
                                      bf16x8 b[2][2]) {
#pragma unroll
  for (int n = 0; n < 2; ++n) {
    int row = rB + (nh * 2 + n) * 16 + lc;
#pragma unroll
    for (int kk = 0; kk < 2; ++kk) b[n][kk] = lds_frag(reg, row, kk * 4 + lr);
  }
}

__device__ __forceinline__ void mfma_quad(const bf16x8 a[4][2], const bf16x8 b[2][2],
                                          f32x4 acc[8][4], int mh, int nh) {
  __builtin_amdgcn_s_setprio(1);
#pragma unroll
  for (int m = 0; m < 4; ++m)
#pragma unroll
    for (int n = 0; n < 2; ++n)
#pragma unroll
      for (int kk = 0; kk < 2; ++kk)
        acc[mh * 4 + m][nh * 2 + n] = __builtin_amdgcn_mfma_f32_16x16x32_bf16(
            a[m][kk], b[n][kk], acc[mh * 4 + m][nh * 2 + n], 0, 0, 0);
  __builtin_amdgcn_s_setprio(0);
}

__global__ __launch_bounds__(512, 2) void gemm_kernel(
    const unsigned short* __restrict__ xb, const unsigned short* __restrict__ wb,
    const float* __restrict__ bias, float* __restrict__ out) {
  // LDS: 2 bufs x [A0|A1|B0|B1], each region 128x64 bf16 (8192 ushort) = 128 KiB
  __shared__ unsigned short lds[65536];

  int bid = blockIdx.x;
  int swz = (bid & 7) * 64 + (bid >> 3);   // bijective: 512 % 8 == 0
  int mt = swz >> 4, nt = swz & 15;
  int m0 = mt * 256, n0 = nt * 256;

  int tid = threadIdx.x;
  int w = tid >> 6, lane = tid & 63;
  int wr = w >> 2, wc = w & 3;             // 2 x 4 waves; per-wave out = 128 x 64
  int lr = lane >> 4, lc = lane & 15;
  int rB = (wc & 1) * 64;

  // staging: chunk = l*512 + tid (16B units), row = chunk>>3, phys col = chunk&7,
  // logical (global) col = (chunk&7) ^ (row&7). Row+64 keeps the same swizzle.
  int r0 = tid >> 3, c0g = (tid & 7) ^ (r0 & 7);
  int co0 = tid * 8, co1 = (512 + tid) * 8;

  const unsigned short* sA00 = xb + (size_t)(m0 + r0) * K_DIM + c0g * 8;
  const unsigned short* sB00 = wb + (size_t)(n0 + r0) * K_DIM + c0g * 8;

#define STAGE_A(h, buf, kt) do { \
    const unsigned short* _p = sA00 + (size_t)(h) * 128 * K_DIM + (size_t)(kt); \
    async_copy16(_p, &lds[(buf) * 32768 + (h) * 8192 + co0]); \
    async_copy16(_p + (size_t)64 * K_DIM, &lds[(buf) * 32768 + (h) * 8192 + co1]); } while (0)
#define STAGE_B(h, buf, kt) do { \
    const unsigned short* _p = sB00 + (size_t)(h) * 128 * K_DIM + (size_t)(kt); \
    async_copy16(_p, &lds[(buf) * 32768 + 16384 + (h) * 8192 + co0]); \
    async_copy16(_p + (size_t)64 * K_DIM, &lds[(buf) * 32768 + 16384 + (h) * 8192 + co1]); } while (0)

  const unsigned short* aR[2] = { &lds[wr * 8192], &lds[32768 + wr * 8192] };
  const unsigned short* bR[2] = { &lds[16384 + (wc >> 1) * 8192],
                                  &lds[32768 + 16384 + (wc >> 1) * 8192] };

  f32x4 acc[8][4];
#pragma unroll
  for (int i = 0; i < 8; ++i)
#pragma unroll
    for (int j = 0; j < 4; ++j) acc[i][j] = f32x4{0.f, 0.f, 0.f, 0.f};

  // prologue: tile0 -> buf0 (8 loads, oldest), tile1 -> buf1 (8 loads)
  STAGE_B(0, 0, 0); STAGE_B(1, 0, 0); STAGE_A(0, 0, 0); STAGE_A(1, 0, 0);
  STAGE_B(0, 1, 64); STAGE_B(1, 1, 64); STAGE_A(0, 1, 64); STAGE_A(1, 1, 64);
  WAIT_VM8();                // tile0 fully landed; tile1's 8 in flight
  BAR(); SB();

  bf16x8 aU[4][2], aV[4][2], b0[2][2], b1[2][2];

#pragma unroll 1
  for (int i = 0; i < 32; ++i) {
    int k2 = ((2 * i + 2) & 63) * 64;      // tile t+2 (wrap harmless at tail)
    int k3 = ((2 * i + 3) & 63) * 64;      // tile t+3

    // ---- P1: reads {aU, b0}; MFMA Q(0,0)
    readA(aR[0], 0, lc, lr, aU); readB(bR[0], 0, rB, lc, lr, b0);
    HINT_LGKM8();
    SB(); BAR(); WAIT_LGKM0();
    mfma_quad(aU, b0, acc, 0, 0);
    SB(); BAR(); SB();
    // ---- P2: reads {b1}; MFMA Q(0,1)
    readB(bR[0], 1, rB, lc, lr, b1);
    SB(); BAR(); WAIT_LGKM0();
    mfma_quad(aU, b1, acc, 0, 1);
    SB(); BAR(); SB();
    // ---- P3: reads {aV}; stage B0,B1(t+2)->buf0 [B(t) dead after P2]; MFMA Q(1,1)
    readA(aR[0], 1, lc, lr, aV);
    SB(); STAGE_B(0, 0, k2); STAGE_B(1, 0, k2);
    SB(); BAR(); WAIT_LGKM0();
    mfma_quad(aV, b1, acc, 1, 1);
    SB(); BAR(); SB();
    // ---- P4: no reads; stage A0,A1(t+2)->buf0 [A(t) dead after P3]; MFMA Q(1,0)
    SB(); STAGE_A(0, 0, k2); STAGE_A(1, 0, k2);
    SB(); BAR();
    mfma_quad(aV, b0, acc, 1, 0);
    SB(); WAIT_VM8(); BAR(); SB();   // seam: tile t+1 fully landed (P3+P4 = 8 newer)
    // ---- P5: reads {aU, b0} from buf1; MFMA Q(0,0)
    readA(aR[1], 0, lc, lr, aU); readB(bR[1], 0, rB, lc, lr, b0);
    HINT_LGKM8();
    SB(); BAR(); WAIT_LGKM0();
    mfma_quad(aU, b0, acc, 0, 0);
    SB(); BAR(); SB();
    // ---- P6: reads {b1}; MFMA Q(0,1)
    readB(bR[1], 1, rB, lc, lr, b1);
    SB(); BAR(); WAIT_LGKM0();
    mfma_quad(aU, b1, acc, 0, 1);
    SB(); BAR(); SB();
    // ---- P7: reads {aV}; stage B0,B1(t+3)->buf1 [B(t+1) dead after P6]; MFMA Q(1,1)
    readA(aR[1], 1, lc, lr, aV);
    SB(); STAGE_B(0, 1, k3); STAGE_B(1, 1, k3);
    SB(); BAR(); WAIT_LGKM0();
    mfma_quad(aV, b1, acc, 1, 1);
    SB(); BAR(); SB();
    // ---- P8: no reads; stage A0,A1(t+3)->buf1 [A(t+1) dead after P7]; MFMA Q(1,0)
    SB(); STAGE_A(0, 1, k3); STAGE_A(1, 1, k3);
    SB(); BAR();
    mfma_quad(aV, b0, acc, 1, 0);
    SB(); WAIT_VM8(); BAR(); SB();   // seam: tile t+2 fully landed (P7+P8 = 8 newer)
  }
  asm volatile("s_waitcnt vmcnt(0) lgkmcnt(0)" ::: "memory");  // drain tail strays

  // epilogue: 16x16 C/D layout col=lane&15, row=(lane>>4)*4+j  [m89/m91]
#pragma unroll
  for (int ni = 0; ni < 4; ++ni) {
    int n = n0 + wc * 64 + ni * 16 + lc;
    float bv = bias[n];
#pragma unroll
    for (int mi = 0; mi < 8; ++mi) {
      int mb = m0 + wr * 128 + mi * 16 + lr * 4;
#pragma unroll
      for (int j = 0; j < 4; ++j)
        out[(size_t)(mb + j) * N_DIM + n] = acc[mi][ni][j] + bv;
    }
  }
#undef STAGE_A
#undef STAGE_B
}

extern "C" void kernel_launch(void* const* d_in, const int* in_sizes, int n_in,
                              void* d_out, int out_size, void* d_ws, size_t ws_size,
                              hipStream_t stream) {
  const float* x     = (const float*)d_in[0];
  const int*   Wq    = (const int*)d_in[1];
  const float* scale = (const float*)d_in[2];
  const float* zero  = (const float*)d_in[3];
  const float* lA    = (const float*)d_in[4];
  const float* lB    = (const float*)d_in[5];
  const float* bias  = (const float*)d_in[6];
  float* out = (float*)d_out;

  unsigned short* xb = (unsigned short*)d_ws;                                      // 64 MB
  unsigned short* wb = (unsigned short*)((char*)d_ws + (size_t)M_DIM * K_DIM * 2); // +32 MB

  prep_kernel<<<6144, 256, 0, stream>>>(x, xb, Wq, scale, zero, lA, lB, wb);
  gemm_kernel<<<512, 512, 0, stream>>>(xb, wb, bias, out);
}

// Round 9
// 310.540 us; speedup vs baseline: 9.9164x; 1.0468x over previous
//
#include <hip/hip_runtime.h>
#include <hip/hip_bf16.h>
#include <stdint.h>

#define M_DIM 8192
#define N_DIM 4096
#define K_DIM 4096

typedef __attribute__((ext_vector_type(8))) __bf16 bf16x8;
typedef __attribute__((ext_vector_type(4))) float f32x4;

__device__ inline unsigned short f2bf(float f) {
  unsigned u = __builtin_bit_cast(unsigned, f);
  u += 0x7FFF + ((u >> 16) & 1);   // round-to-nearest-even
  return (unsigned short)(u >> 16);
}

__device__ inline void async_copy16(const void* g, void* l) {
  __builtin_amdgcn_global_load_lds(
      (const __attribute__((address_space(1))) unsigned int*)g,
      (__attribute__((address_space(3))) unsigned int*)l, 16, 0, 0);
}

// ---------- fused prep: blocks [0,4096) build W_eff; [4096,6144) cvt x ----------
__global__ __launch_bounds__(256) void prep_kernel(
    const float* __restrict__ x, unsigned short* __restrict__ xb,
    const int* __restrict__ Wq, const float* __restrict__ scale,
    const float* __restrict__ zero, const float* __restrict__ A,
    const float* __restrict__ Bm, unsigned short* __restrict__ Weff) {
  int t = threadIdx.x;
  if (blockIdx.x < 4096) {
    __shared__ float sA[64 * 17];
    __shared__ float sB[16 * 64];
    int bo = blockIdx.x >> 6;
    int bi = blockIdx.x & 63;
    int o0 = bo * 64, i0 = bi * 64;
    for (int j = t; j < 1024; j += 256) sA[(j >> 4) * 17 + (j & 15)] = A[i0 * 16 + j];
    for (int j = t; j < 1024; j += 256) sB[j] = Bm[(j >> 6) * N_DIM + o0 + (j & 63)];
    __syncthreads();
    for (int e = 0; e < 16; ++e) {
      int idx = e * 256 + t;
      int oo = idx >> 6, ii = idx & 63;
      int o = o0 + oo;
      float sc = scale[o * 64 + bi];
      float zp = zero[o * 64 + bi];
      float w = ((float)Wq[(size_t)o * K_DIM + i0 + ii] - zp) * sc;
      float acc = 0.f;
#pragma unroll
      for (int r = 0; r < 16; ++r) acc += sA[ii * 17 + r] * sB[r * 64 + oo];
      w += 2.0f * acc;
      Weff[(size_t)o * K_DIM + i0 + ii] = f2bf(w);
    }
  } else {
    int i = (blockIdx.x - 4096) * 256 + t;
    int stride = 2048 * 256;
    int n4 = (M_DIM * K_DIM) / 4;
    for (; i < n4; i += stride) {
      float4 v = reinterpret_cast<const float4*>(x)[i];
      ushort4 o;
      o.x = f2bf(v.x); o.y = f2bf(v.y); o.z = f2bf(v.z); o.w = f2bf(v.w);
      reinterpret_cast<ushort4*>(xb)[i] = o;
    }
  }
}

// ---------- 256x256 8-phase bf16 GEMM: read-ahead, wait-before-barrier seams ----
#define BAR() __builtin_amdgcn_s_barrier()
#define SB()  __builtin_amdgcn_sched_barrier(0)
#define WAIT_VM4() do { asm volatile("s_waitcnt vmcnt(4)" ::: "memory"); } while (0)

// swizzled LDS fragment read: region is [128][64] bf16 half-tile; 16B chunk c of
// row lives at physical column (c ^ (row&7)). Measured 0 bank conflicts (R2/R4/R5).
__device__ __forceinline__ bf16x8 lds_frag(const unsigned short* region, int row, int c) {
  return *reinterpret_cast<const bf16x8*>(region + row * 64 + ((c ^ (row & 7)) << 3));
}

__device__ __forceinline__ void readA(const unsigned short* reg, int mh, int lc, int lr,
                                      bf16x8 a[4][2]) {
#pragma unroll
  for (int m = 0; m < 4; ++m) {
    int row = mh * 64 + m * 16 + lc;
#pragma unroll
    for (int kk = 0; kk < 2; ++kk) a[m][kk] = lds_frag(reg, row, kk * 4 + lr);
  }
}

__device__ __forceinline__ void readB(const unsigned short* reg, int nh, int rB, int lc, int lr,
                                      bf16x8 b[2][2]) {
#pragma unroll
  for (int n = 0; n < 2; ++n) {
    int row = rB + (nh * 2 + n) * 16 + lc;
#pragma unroll
    for (int kk = 0; kk < 2; ++kk) b[n][kk] = lds_frag(reg, row, kk * 4 + lr);
  }
}

// kk-OUTER: 8 independent MFMAs between accumulator reuses (hides MFMA latency
// at 2 waves/SIMD; numerically identical to kk-inner).
__device__ __forceinline__ void mfma_quad(const bf16x8 a[4][2], const bf16x8 b[2][2],
                                          f32x4 acc[8][4], int mh, int nh) {
  __builtin_amdgcn_s_setprio(1);
#pragma unroll
  for (int kk = 0; kk < 2; ++kk)
#pragma unroll
    for (int m = 0; m < 4; ++m)
#pragma unroll
      for (int n = 0; n < 2; ++n)
        acc[mh * 4 + m][nh * 2 + n] = __builtin_amdgcn_mfma_f32_16x16x32_bf16(
            a[m][kk], b[n][kk], acc[mh * 4 + m][nh * 2 + n], 0, 0, 0);
  __builtin_amdgcn_s_setprio(0);
}

__global__ __launch_bounds__(512, 2) void gemm_kernel(
    const unsigned short* __restrict__ xb, const unsigned short* __restrict__ wb,
    const float* __restrict__ bias, float* __restrict__ out) {
  // LDS: 2 bufs x [A0|A1|B0|B1], each region 128x64 bf16 (8192 ushort) = 128 KiB
  __shared__ unsigned short lds[65536];

  int bid = blockIdx.x;
  int swz = (bid & 7) * 64 + (bid >> 3);   // bijective: 512 % 8 == 0
  int mt = swz >> 4, nt = swz & 15;
  int m0 = mt * 256, n0 = nt * 256;

  int tid = threadIdx.x;
  int w = tid >> 6, lane = tid & 63;
  int wr = w >> 2, wc = w & 3;             // 2 x 4 waves; per-wave out = 128 x 64
  int lr = lane >> 4, lc = lane & 15;
  int rB = (wc & 1) * 64;

  // staging: chunk = l*512 + tid (16B units), row = chunk>>3, phys col = chunk&7,
  // logical (global) col = (chunk&7) ^ (row&7). Row+64 keeps the same swizzle.
  int r0 = tid >> 3, c0g = (tid & 7) ^ (r0 & 7);
  int co0 = tid * 8, co1 = (512 + tid) * 8;

  const unsigned short* sA00 = xb + (size_t)(m0 + r0) * K_DIM + c0g * 8;
  const unsigned short* sB00 = wb + (size_t)(n0 + r0) * K_DIM + c0g * 8;

#define STAGE_A(h, buf, kt) do { \
    const unsigned short* _p = sA00 + (size_t)(h) * 128 * K_DIM + (size_t)(kt); \
    async_copy16(_p, &lds[(buf) * 32768 + (h) * 8192 + co0]); \
    async_copy16(_p + (size_t)64 * K_DIM, &lds[(buf) * 32768 + (h) * 8192 + co1]); } while (0)
#define STAGE_B(h, buf, kt) do { \
    const unsigned short* _p = sB00 + (size_t)(h) * 128 * K_DIM + (size_t)(kt); \
    async_copy16(_p, &lds[(buf) * 32768 + 16384 + (h) * 8192 + co0]); \
    async_copy16(_p + (size_t)64 * K_DIM, &lds[(buf) * 32768 + 16384 + (h) * 8192 + co1]); } while (0)

  const unsigned short* aR[2] = { &lds[wr * 8192], &lds[32768 + wr * 8192] };
  const unsigned short* bR[2] = { &lds[16384 + (wc >> 1) * 8192],
                                  &lds[32768 + 16384 + (wc >> 1) * 8192] };

  f32x4 acc[8][4];
#pragma unroll
  for (int i = 0; i < 8; ++i)
#pragma unroll
    for (int j = 0; j < 4; ++j) acc[i][j] = f32x4{0.f, 0.f, 0.f, 0.f};

  // prologue: buf0 <- tile0 (8 loads, oldest), buf1.{B0,B1,A0} <- tile1 (6 loads;
  // buf1.A1 staged at P1 of iter 0, matching steady state)
  STAGE_B(0, 0, 0); STAGE_B(1, 0, 0); STAGE_A(0, 0, 0); STAGE_A(1, 0, 0);
  STAGE_B(0, 1, 64); STAGE_B(1, 1, 64); STAGE_A(0, 1, 64);
  asm volatile("s_waitcnt vmcnt(6)" ::: "memory");   // tile0 fully landed (all waves...
  BAR(); SB();                                       // ...guaranteed after this barrier)
  bf16x8 aU[4][2], aV[4][2], b0[2][2], b1[2][2];
  readA(aR[0], 0, lc, lr, aU); readB(bR[0], 0, rB, lc, lr, b0);  // pre-read P1 operands
  SB();

#pragma unroll 1
  for (int i = 0; i < 32; ++i) {
    int k1 = (2 * i + 1) * 64;             // tile t+1 (never wraps)
    int k2 = ((2 * i + 2) & 63) * 64;      // tile t+2 (wrap harmless at tail)
    int k3 = ((2 * i + 3) & 63) * 64;      // tile t+3

    // P1: MFMA Q00(aU,b0)   read b1<-buf0.B1        stage buf1.A1 <- t+1
    readB(bR[0], 1, rB, lc, lr, b1);
    SB(); STAGE_A(1, 1, k1); SB();
    mfma_quad(aU, b0, acc, 0, 0);
    SB(); BAR(); SB();
    // P2: MFMA Q01(aU,b1)   read aV<-buf0.A1        stage buf0.B0 <- t+2
    readA(aR[0], 1, lc, lr, aV);
    SB(); STAGE_B(0, 0, k2); SB();
    mfma_quad(aU, b1, acc, 0, 1);
    SB(); BAR(); SB();
    // P3: MFMA Q10(aV,b0)   no reads                stage buf0.B1 <- t+2
    //     SEAM: drain to 4 -> all of buf1(t+1) landed in EVERY wave before BAR
    SB(); STAGE_B(1, 0, k2); SB();
    mfma_quad(aV, b0, acc, 1, 0);
    SB(); WAIT_VM4(); BAR(); SB();
    // P4: MFMA Q11(aV,b1)   read aU,b0<-buf1 (t+1)  stage buf0.A0 <- t+2
    readA(aR[1], 0, lc, lr, aU); readB(bR[1], 0, rB, lc, lr, b0);
    SB(); STAGE_A(0, 0, k2); SB();
    mfma_quad(aV, b1, acc, 1, 1);
    SB(); BAR(); SB();
    // P5: MFMA Q00(aU,b0)   read b1<-buf1.B1        stage buf0.A1 <- t+2
    readB(bR[1], 1, rB, lc, lr, b1);
    SB(); STAGE_A(1, 0, k2); SB();
    mfma_quad(aU, b0, acc, 0, 0);
    SB(); BAR(); SB();
    // P6: MFMA Q01(aU,b1)   read aV<-buf1.A1        stage buf1.B0 <- t+3
    readA(aR[1], 1, lc, lr, aV);
    SB(); STAGE_B(0, 1, k3); SB();
    mfma_quad(aU, b1, acc, 0, 1);
    SB(); BAR(); SB();
    // P7: MFMA Q10(aV,b0)   no reads                stage buf1.B1 <- t+3
    //     SEAM: drain to 4 -> all of buf0(t+2) landed in EVERY wave before BAR
    SB(); STAGE_B(1, 1, k3); SB();
    mfma_quad(aV, b0, acc, 1, 0);
    SB(); WAIT_VM4(); BAR(); SB();
    // P8: MFMA Q11(aV,b1)   read aU,b0<-buf0 (t+2)  stage buf1.A0 <- t+3
    readA(aR[0], 0, lc, lr, aU); readB(bR[0], 0, rB, lc, lr, b0);
    SB(); STAGE_A(0, 1, k3); SB();
    mfma_quad(aV, b1, acc, 1, 1);
    SB(); BAR(); SB();
  }
  asm volatile("s_waitcnt vmcnt(0) lgkmcnt(0)" ::: "memory");  // drain tail strays

  // epilogue: 16x16 C/D layout col=lane&15, row=(lane>>4)*4+j  [m89/m91]
#pragma unroll
  for (int ni = 0; ni < 4; ++ni) {
    int n = n0 + wc * 64 + ni * 16 + lc;
    float bv = bias[n];
#pragma unroll
    for (int mi = 0; mi < 8; ++mi) {
      int mb = m0 + wr * 128 + mi * 16 + lr * 4;
#pragma unroll
      for (int j = 0; j < 4; ++j)
        out[(size_t)(mb + j) * N_DIM + n] = acc[mi][ni][j] + bv;
    }
  }
#undef STAGE_A
#undef STAGE_B
}

extern "C" void kernel_launch(void* const* d_in, const int* in_sizes, int n_in,
                              void* d_out, int out_size, void* d_ws, size_t ws_size,
                              hipStream_t stream) {
  const float* x     = (const float*)d_in[0];
  const int*   Wq    = (const int*)d_in[1];
  const float* scale = (const float*)d_in[2];
  const float* zero  = (const float*)d_in[3];
  const float* lA    = (const float*)d_in[4];
  const float* lB    = (const float*)d_in[5];
  const float* bias  = (const float*)d_in[6];
  float* out = (float*)d_out;

  unsigned short* xb = (unsigned short*)d_ws;                                      // 64 MB
  unsigned short* wb = (unsigned short*)((char*)d_ws + (size_t)M_DIM * K_DIM * 2); // +32 MB

  prep_kernel<<<6144, 256, 0, stream>>>(x, xb, Wq, scale, zero, lA, lB, wb);
  gemm_kernel<<<512, 512, 0, stream>>>(xb, wb, bias, out);
}

// Round 10
// 282.926 us; speedup vs baseline: 10.8843x; 1.0976x over previous
//
#include <hip/hip_runtime.h>
#include <hip/hip_bf16.h>
#include <stdint.h>

#define M_DIM 8192
#define N_DIM 4096
#define K_DIM 4096

typedef __attribute__((ext_vector_type(8))) __bf16 bf16x8;
typedef __attribute__((ext_vector_type(4))) float f32x4;

__device__ inline unsigned short f2bf(float f) {
  unsigned u = __builtin_bit_cast(unsigned, f);
  u += 0x7FFF + ((u >> 16) & 1);   // round-to-nearest-even
  return (unsigned short)(u >> 16);
}

__device__ inline void async_copy16(const void* g, void* l) {
  __builtin_amdgcn_global_load_lds(
      (const __attribute__((address_space(1))) unsigned int*)g,
      (__attribute__((address_space(3))) unsigned int*)l, 16, 0, 0);
}

// ---------- fused prep: blocks [0,4096) build W_eff; [4096,6144) cvt x ----------
__global__ __launch_bounds__(256) void prep_kernel(
    const float* __restrict__ x, unsigned short* __restrict__ xb,
    const int* __restrict__ Wq, const float* __restrict__ scale,
    const float* __restrict__ zero, const float* __restrict__ A,
    const float* __restrict__ Bm, unsigned short* __restrict__ Weff) {
  int t = threadIdx.x;
  if (blockIdx.x < 4096) {
    __shared__ float sA[64 * 17];
    __shared__ float sB[16 * 64];
    int bo = blockIdx.x >> 6;
    int bi = blockIdx.x & 63;
    int o0 = bo * 64, i0 = bi * 64;
    for (int j = t; j < 1024; j += 256) sA[(j >> 4) * 17 + (j & 15)] = A[i0 * 16 + j];
    for (int j = t; j < 1024; j += 256) sB[j] = Bm[(j >> 6) * N_DIM + o0 + (j & 63)];
    __syncthreads();
#pragma unroll
    for (int e = 0; e < 2; ++e) {
      int slot = e * 256 + t;            // 0..511; 8 consecutive ii per slot
      int oo = slot >> 3, ii0 = (slot & 7) * 8;
      int o = o0 + oo;
      float sc = scale[o * 64 + bi];
      float zp = zero[o * 64 + bi];
      const int* qp = &Wq[(size_t)o * K_DIM + i0 + ii0];
      int4 q0 = *reinterpret_cast<const int4*>(qp);
      int4 q1 = *reinterpret_cast<const int4*>(qp + 4);
      int qv[8] = {q0.x, q0.y, q0.z, q0.w, q1.x, q1.y, q1.z, q1.w};
      ushort4 r0, r1;
      unsigned short rr[8];
#pragma unroll
      for (int j = 0; j < 8; ++j) {
        float acc = 0.f;
#pragma unroll
        for (int r = 0; r < 16; ++r) acc += sA[(ii0 + j) * 17 + r] * sB[r * 64 + oo];
        rr[j] = f2bf(((float)qv[j] - zp) * sc + 2.0f * acc);
      }
      r0 = ushort4{rr[0], rr[1], rr[2], rr[3]};
      r1 = ushort4{rr[4], rr[5], rr[6], rr[7]};
      ushort4* wp = reinterpret_cast<ushort4*>(&Weff[(size_t)o * K_DIM + i0 + ii0]);
      wp[0] = r0; wp[1] = r1;
    }
  } else {
    int i = (blockIdx.x - 4096) * 256 + t;
    int stride = 2048 * 256;
    int n4 = (M_DIM * K_DIM) / 4;
    for (; i < n4; i += stride) {
      float4 v = reinterpret_cast<const float4*>(x)[i];
      ushort4 o;
      o.x = f2bf(v.x); o.y = f2bf(v.y); o.z = f2bf(v.z); o.w = f2bf(v.w);
      reinterpret_cast<ushort4*>(xb)[i] = o;
    }
  }
}

// ---------- 256x256 8-phase bf16 GEMM: read-ahead, minimal sched pinning ----------
#define BAR() __builtin_amdgcn_s_barrier()
#define SB()  __builtin_amdgcn_sched_barrier(0)
#define WAIT_VM4() do { asm volatile("s_waitcnt vmcnt(4)" ::: "memory"); } while (0)

// swizzled LDS fragment read: region is [128][64] bf16 half-tile; 16B chunk c of
// row lives at physical column (c ^ (row&7)). Measured 0 bank conflicts (R2/R4/R5/R9).
__device__ __forceinline__ bf16x8 lds_frag(const unsigned short* region, int row, int c) {
  return *reinterpret_cast<const bf16x8*>(region + row * 64 + ((c ^ (row & 7)) << 3));
}

__device__ __forceinline__ void readA(const unsigned short* reg, int mh, int lc, int lr,
                                      bf16x8 a[4][2]) {
#pragma unroll
  for (int m = 0; m < 4; ++m) {
    int row = mh * 64 + m * 16 + lc;
#pragma unroll
    for (int kk = 0; kk < 2; ++kk) a[m][kk] = lds_frag(reg, row, kk * 4 + lr);
  }
}

__device__ __forceinline__ void readB(const unsigned short* reg, int nh, int rB, int lc, int lr,
                                      bf16x8 b[2][2]) {
#pragma unroll
  for (int n = 0; n < 2; ++n) {
    int row = rB + (nh * 2 + n) * 16 + lc;
#pragma unroll
    for (int kk = 0; kk < 2; ++kk) b[n][kk] = lds_frag(reg, row, kk * 4 + lr);
  }
}

// kk-OUTER, no setprio (m190: setprio negative on lockstep GEMM).
__device__ __forceinline__ void mfma_quad(const bf16x8 a[4][2], const bf16x8 b[2][2],
                                          f32x4 acc[8][4], int mh, int nh) {
#pragma unroll
  for (int kk = 0; kk < 2; ++kk)
#pragma unroll
    for (int m = 0; m < 4; ++m)
#pragma unroll
      for (int n = 0; n < 2; ++n)
        acc[mh * 4 + m][nh * 2 + n] = __builtin_amdgcn_mfma_f32_16x16x32_bf16(
            a[m][kk], b[n][kk], acc[mh * 4 + m][nh * 2 + n], 0, 0, 0);
}

__global__ __launch_bounds__(512, 2) void gemm_kernel(
    const unsigned short* __restrict__ xb, const unsigned short* __restrict__ wb,
    const float* __restrict__ bias, float* __restrict__ out) {
  // LDS: 2 bufs x [A0|A1|B0|B1], each region 128x64 bf16 (8192 ushort) = 128 KiB
  __shared__ unsigned short lds[65536];

  int bid = blockIdx.x;
  int swz = (bid & 7) * 64 + (bid >> 3);   // bijective: 512 % 8 == 0
  int mt = swz >> 4, nt = swz & 15;
  int m0 = mt * 256, n0 = nt * 256;

  int tid = threadIdx.x;
  int w = tid >> 6, lane = tid & 63;
  int wr = w >> 2, wc = w & 3;             // 2 x 4 waves; per-wave out = 128 x 64
  int lr = lane >> 4, lc = lane & 15;
  int rB = (wc & 1) * 64;

  // staging: chunk = l*512 + tid (16B units), row = chunk>>3, phys col = chunk&7,
  // logical (global) col = (chunk&7) ^ (row&7). Row+64 keeps the same swizzle.
  int r0 = tid >> 3, c0g = (tid & 7) ^ (r0 & 7);
  int co0 = tid * 8, co1 = (512 + tid) * 8;

  const unsigned short* sA00 = xb + (size_t)(m0 + r0) * K_DIM + c0g * 8;
  const unsigned short* sB00 = wb + (size_t)(n0 + r0) * K_DIM + c0g * 8;

#define STAGE_A(h, buf, kt) do { \
    const unsigned short* _p = sA00 + (size_t)(h) * 128 * K_DIM + (size_t)(kt); \
    async_copy16(_p, &lds[(buf) * 32768 + (h) * 8192 + co0]); \
    async_copy16(_p + (size_t)64 * K_DIM, &lds[(buf) * 32768 + (h) * 8192 + co1]); } while (0)
#define STAGE_B(h, buf, kt) do { \
    const unsigned short* _p = sB00 + (size_t)(h) * 128 * K_DIM + (size_t)(kt); \
    async_copy16(_p, &lds[(buf) * 32768 + 16384 + (h) * 8192 + co0]); \
    async_copy16(_p + (size_t)64 * K_DIM, &lds[(buf) * 32768 + 16384 + (h) * 8192 + co1]); } while (0)

  const unsigned short* aR[2] = { &lds[wr * 8192], &lds[32768 + wr * 8192] };
  const unsigned short* bR[2] = { &lds[16384 + (wc >> 1) * 8192],
                                  &lds[32768 + 16384 + (wc >> 1) * 8192] };

  f32x4 acc[8][4];
#pragma unroll
  for (int i = 0; i < 8; ++i)
#pragma unroll
    for (int j = 0; j < 4; ++j) acc[i][j] = f32x4{0.f, 0.f, 0.f, 0.f};

  // prologue: buf0 <- tile0 (8 loads, oldest), buf1.{B0,B1,A0} <- tile1 (6 loads;
  // buf1.A1 staged at P1 of iter 0, matching steady state)
  STAGE_B(0, 0, 0); STAGE_B(1, 0, 0); STAGE_A(0, 0, 0); STAGE_A(1, 0, 0);
  STAGE_B(0, 1, 64); STAGE_B(1, 1, 64); STAGE_A(0, 1, 64);
  asm volatile("s_waitcnt vmcnt(6)" ::: "memory");   // tile0 landed (every wave,
  SB(); BAR(); SB();                                 // before the barrier)
  bf16x8 aU[4][2], aV[4][2], b0[2][2], b1[2][2];
  readA(aR[0], 0, lc, lr, aU); readB(bR[0], 0, rB, lc, lr, b0);  // pre-read P1 operands

#pragma unroll 1
  for (int i = 0; i < 32; ++i) {
    int k1 = (2 * i + 1) * 64;             // tile t+1 (never wraps)
    int k2 = ((2 * i + 2) & 63) * 64;      // tile t+2 (wrap harmless at tail)
    int k3 = ((2 * i + 3) & 63) * 64;      // tile t+3

    // P1: MFMA Q00(aU,b0)   read b1<-buf0.B1        stage buf1.A1 <- t+1
    readB(bR[0], 1, rB, lc, lr, b1);
    STAGE_A(1, 1, k1);
    mfma_quad(aU, b0, acc, 0, 0);
    BAR(); SB();
    // P2: MFMA Q01(aU,b1)   read aV<-buf0.A1        stage buf0.B0 <- t+2
    readA(aR[0], 1, lc, lr, aV);
    STAGE_B(0, 0, k2);
    mfma_quad(aU, b1, acc, 0, 1);
    BAR(); SB();
    // P3: MFMA Q10(aV,b0)   no reads                stage buf0.B1 <- t+2
    //     SEAM: drain to 4 -> all of buf1(t+1) landed in EVERY wave before BAR
    STAGE_B(1, 0, k2);
    mfma_quad(aV, b0, acc, 1, 0);
    WAIT_VM4(); SB(); BAR(); SB();
    // P4: MFMA Q11(aV,b1)   read aU,b0<-buf1 (t+1)  stage buf0.A0 <- t+2
    readA(aR[1], 0, lc, lr, aU); readB(bR[1], 0, rB, lc, lr, b0);
    STAGE_A(0, 0, k2);
    mfma_quad(aV, b1, acc, 1, 1);
    BAR(); SB();
    // P5: MFMA Q00(aU,b0)   read b1<-buf1.B1        stage buf0.A1 <- t+2
    readB(bR[1], 1, rB, lc, lr, b1);
    STAGE_A(1, 0, k2);
    mfma_quad(aU, b0, acc, 0, 0);
    BAR(); SB();
    // P6: MFMA Q01(aU,b1)   read aV<-buf1.A1        stage buf1.B0 <- t+3
    readA(aR[1], 1, lc, lr, aV);
    STAGE_B(0, 1, k3);
    mfma_quad(aU, b1, acc, 0, 1);
    BAR(); SB();
    // P7: MFMA Q10(aV,b0)   no reads                stage buf1.B1 <- t+3
    //     SEAM: drain to 4 -> all of buf0(t+2) landed in EVERY wave before BAR
    STAGE_B(1, 1, k3);
    mfma_quad(aV, b0, acc, 1, 0);
    WAIT_VM4(); SB(); BAR(); SB();
    // P8: MFMA Q11(aV,b1)   read aU,b0<-buf0 (t+2)  stage buf1.A0 <- t+3
    readA(aR[0], 0, lc, lr, aU); readB(bR[0], 0, rB, lc, lr, b0);
    STAGE_A(0, 1, k3);
    mfma_quad(aV, b1, acc, 1, 1);
    BAR(); SB();
  }
  asm volatile("s_waitcnt vmcnt(0) lgkmcnt(0)" ::: "memory");  // drain tail strays

  // epilogue: 16x16 C/D layout col=lane&15, row=(lane>>4)*4+j  [m89/m91]
  // nontemporal stores: keep xb/wb resident in L2/L3 (out is write-once stream)
#pragma unroll
  for (int ni = 0; ni < 4; ++ni) {
    int n = n0 + wc * 64 + ni * 16 + lc;
    float bv = bias[n];
#pragma unroll
    for (int mi = 0; mi < 8; ++mi) {
      int mb = m0 + wr * 128 + mi * 16 + lr * 4;
#pragma unroll
      for (int j = 0; j < 4; ++j)
        __builtin_nontemporal_store(acc[mi][ni][j] + bv,
                                    &out[(size_t)(mb + j) * N_DIM + n]);
    }
  }
#undef STAGE_A
#undef STAGE_B
}

extern "C" void kernel_launch(void* const* d_in, const int* in_sizes, int n_in,
                              void* d_out, int out_size, void* d_ws, size_t ws_size,
                              hipStream_t stream) {
  const float* x     = (const float*)d_in[0];
  const int*   Wq    = (const int*)d_in[1];
  const float* scale = (const float*)d_in[2];
  const float* zero  = (const float*)d_in[3];
  const float* lA    = (const float*)d_in[4];
  const float* lB    = (const float*)d_in[5];
  const float* bias  = (const float*)d_in[6];
  float* out = (float*)d_out;

  unsigned short* xb = (unsigned short*)d_ws;                                      // 64 MB
  unsigned short* wb = (unsigned short*)((char*)d_ws + (size_t)M_DIM * K_DIM * 2); // +32 MB

  prep_kernel<<<6144, 256, 0, stream>>>(x, xb, Wq, scale, zero, lA, lB, wb);
  gemm_kernel<<<512, 512, 0, stream>>>(xb, wb, bias, out);
}